// Round 9
// baseline (486.142 us; speedup 1.0000x reference)
//
#include <hip/hip_runtime.h>
#include <math.h>

#define B_ 4
#define CIN_ 32
#define HID_ 32
#define T_ 31
#define H_ 96
#define W_ 96
#define SP_ (H_*W_)
#define TC_ 8          // t-steps per conv block
#define NCH_ 4         // t-chunks

typedef _Float16 half8 __attribute__((ext_vector_type(8)));
typedef float f32x4 __attribute__((ext_vector_type(4)));
typedef float f32x16 __attribute__((ext_vector_type(16)));

static __device__ inline unsigned int packzf(float z, float f) {
  unsigned short uz = __builtin_bit_cast(unsigned short, (_Float16)z);
  unsigned short uf = __builtin_bit_cast(unsigned short, (_Float16)f);
  return (unsigned int)uz | ((unsigned int)uf << 16);
}

// ---------------------------------------------------------------------------
// Kernel 0: weights fp32 -> fp16 gate-interleaved MFMA A-fragments.
// wr[((ocg*27 + tap)*64 + lane)*8 + i]
//   m = lane&15: gate = m&1, ch = ocg*8 + (m>>1); oc = gate*32 + ch
//   cin = (lane>>4)*8 + i
// ---------------------------------------------------------------------------
__global__ __launch_bounds__(256) void prep_w_kernel(
    const float* __restrict__ w, _Float16* __restrict__ wr) {
  int idx = blockIdx.x * 256 + threadIdx.x;
  if (idx >= 55296) return;
  int i = idx & 7;
  int lane = (idx >> 3) & 63;
  int rest = idx >> 9;             // ocg*27 + tap
  int tap = rest % 27;
  int ocg = rest / 27;
  int m = lane & 15;
  int cin = (lane >> 4) * 8 + i;
  int oc = (m & 1) * 32 + ocg * 8 + (m >> 1);
  wr[idx] = (_Float16)(w[(oc * CIN_ + cin) * 27 + tap]);
}

// ---------------------------------------------------------------------------
// Kernel 1: t-parallel Conv3d (fp16 MFMA) + activations, PAIR-compute.
// Grid (96,4,4) = 1536 blocks = 6/CU (3 even rounds of 2 co-resident).
// Block 256 thr = 4 waves (wave=ocg), tile 16x6, weights 108 VGPR/wave.
// 6-slot LDS ring (69 KB): pair (t,t+1) reads slices t-1..t+2 (4 slots),
// stages t+3,t+4 into the other 2 slots -> one barrier per 2 t.
// brow reads SHARED across the pair: 96 ds_read_b128 / 2t (was 144).
// Output: (tanh z, sigm f) packed fp16x2 -> d_out as u32 [b][32][t][sp].
// ---------------------------------------------------------------------------
#define PITCH 40
#define SROWS 8
#define SCOLS 18
#define SLICE_HF (SROWS * SCOLS * PITCH)   // 5760 f16 = 11520 B
#define SLOT(s) ((((s) % 6) + 6) % 6)

__global__ __launch_bounds__(256, 2) void conv_gates_mfma(
    const float* __restrict__ in, const _Float16* __restrict__ wr,
    const float* __restrict__ bias, unsigned int* __restrict__ gout) {
  __shared__ _Float16 in_s[6 * SLICE_HF];   // 69120 B

  const int tid = threadIdx.x;
  const int tile = blockIdx.x;   // 0..95
  const int tc0 = blockIdx.y * TC_;
  const int b = blockIdx.z;
  const int x0 = (tile % 6) * 16;
  const int y0 = (tile / 6) * 6;
  const int lane = tid & 63;
  const int ocg = tid >> 6;
  const int px = lane & 15;
  const int kq = lane >> 4;

  // per-wave weights: 27 taps, gate-interleaved 16-slot frags (108 VGPR)
  half8 wreg[27];
  {
    const _Float16* wp = wr + (size_t)ocg * 27 * 512 + lane * 8;
#pragma unroll
    for (int tap = 0; tap < 27; ++tap)
      wreg[tap] = *(const half8*)(wp + tap * 512);
  }

  const int c0 = ocg * 8 + 2 * kq;
  f32x4 bias4;
  bias4[0] = bias[c0];
  bias4[1] = bias[32 + c0];
  bias4[2] = bias[c0 + 1];
  bias4[3] = bias[32 + c0 + 1];

  // staging roles: interior 16 jobs x 16 px (256 rowjobs = 8 rows x 32 cin)
  const int s_xi = tid & 15;
  const int s_q  = tid >> 4;
  const int e_cin = tid & 31;
  const int e_yy  = tid >> 5;       // 0..7
  const int e_gy  = y0 - 1 + e_yy;
  const bool e_ok = ((unsigned)e_gy < (unsigned)H_);

  auto zero_slot = [&](int slot) {
    uint32_t* dz = (uint32_t*)(in_s + slot * SLICE_HF);
    for (int e = tid; e < SLICE_HF / 2; e += 256) dz[e] = 0u;
  };
  auto stage_full = [&](int ts) {
    _Float16* dst = in_s + SLOT(ts) * SLICE_HF;
    const float* sb = in + ((size_t)(b * CIN_) * T_ + ts) * SP_;
#pragma unroll
    for (int k = 0; k < 16; ++k) {
      int rj = k * 16 + s_q;
      int cin = rj & 31;
      int yy = rj >> 5;
      int gy = y0 - 1 + yy;
      float v = 0.f;
      if ((unsigned)gy < (unsigned)H_)
        v = sb[(size_t)cin * (T_ * SP_) + gy * W_ + x0 + s_xi];
      dst[(yy * SCOLS + s_xi + 1) * PITCH + cin] = (_Float16)v;
    }
    float v0 = 0.f, v1 = 0.f;
    if (e_ok) {
      const float* rb = sb + (size_t)e_cin * (T_ * SP_) + e_gy * W_;
      if (x0 > 0) v0 = rb[x0 - 1];
      if (x0 + 16 < W_) v1 = rb[x0 + 16];
    }
    dst[(e_yy * SCOLS + 0) * PITCH + e_cin] = (_Float16)v0;
    dst[(e_yy * SCOLS + 17) * PITCH + e_cin] = (_Float16)v1;
  };

  // prologue: slices tc0-1 .. tc0+2 (tc0+2 <= 26, always real)
  if (tc0 == 0) zero_slot(SLOT(-1)); else stage_full(tc0 - 1);
  stage_full(tc0);
  stage_full(tc0 + 1);
  stage_full(tc0 + 2);
  __syncthreads();

  for (int k = 0; k < TC_ / 2; ++k) {
    const int t0 = tc0 + 2 * k;
    if (t0 >= T_) break;
    const bool hasT1 = (t0 + 1 < T_);
    const int ts0 = t0 + 3, ts1 = t0 + 4;
    const bool stA = (ts0 <= tc0 + TC_) && (ts0 < T_);
    const bool zA  = (ts0 <= tc0 + TC_) && (ts0 == T_);
    const bool stB = (ts1 <= tc0 + TC_) && (ts1 < T_);
    const bool zB  = (ts1 <= tc0 + TC_) && (ts1 == T_);

    // ---- issue stage loads A (slice ts0) ----
    float svA[16], evA0 = 0.f, evA1 = 0.f;
    if (stA) {
      const float* sb = in + ((size_t)(b * CIN_) * T_ + ts0) * SP_;
#pragma unroll
      for (int kk = 0; kk < 16; ++kk) {
        int rj = kk * 16 + s_q;
        int cin = rj & 31;
        int yy = rj >> 5;
        int gy = y0 - 1 + yy;
        svA[kk] = 0.f;
        if ((unsigned)gy < (unsigned)H_)
          svA[kk] = sb[(size_t)cin * (T_ * SP_) + gy * W_ + x0 + s_xi];
      }
      if (e_ok) {
        const float* rb = sb + (size_t)e_cin * (T_ * SP_) + e_gy * W_;
        if (x0 > 0) evA0 = rb[x0 - 1];
        if (x0 + 16 < W_) evA1 = rb[x0 + 16];
      }
    }

    f32x4 acc0[6], acc1[6];
#pragma unroll
    for (int r = 0; r < 6; ++r) { acc0[r] = bias4; acc1[r] = bias4; }

    // ---- slices s=0,1 (t0-1, t0): acc0 taps kd=0,1 ; acc1 kd=0 (s==1) ----
#pragma unroll
    for (int s = 0; s < 2; ++s) {
      const _Float16* sb2 = in_s + SLOT(t0 - 1 + s) * SLICE_HF;
#pragma unroll
      for (int kw = 0; kw < 3; ++kw) {
        half8 brow[8];
#pragma unroll
        for (int rr = 0; rr < 8; ++rr)
          brow[rr] = *(const half8*)(sb2 + (rr * SCOLS + px + kw) * PITCH + kq * 8);
#pragma unroll
        for (int kh = 0; kh < 3; ++kh) {
          const int tap0 = s * 9 + kh * 3 + kw;
#pragma unroll
          for (int r = 0; r < 6; ++r)
            acc0[r] = __builtin_amdgcn_mfma_f32_16x16x32_f16(wreg[tap0], brow[r + kh], acc0[r], 0, 0, 0);
          if (s == 1) {
            const int tap1 = kh * 3 + kw;
#pragma unroll
            for (int r = 0; r < 6; ++r)
              acc1[r] = __builtin_amdgcn_mfma_f32_16x16x32_f16(wreg[tap1], brow[r + kh], acc1[r], 0, 0, 0);
          }
        }
      }
    }

    // ---- write A (slot SLOT(t0+3) = SLOT(t0-3), outside read window) ----
    if (stA) {
      _Float16* dst = in_s + SLOT(ts0) * SLICE_HF;
#pragma unroll
      for (int kk = 0; kk < 16; ++kk) {
        int rj = kk * 16 + s_q;
        int cin = rj & 31;
        int yy = rj >> 5;
        dst[(yy * SCOLS + s_xi + 1) * PITCH + cin] = (_Float16)svA[kk];
      }
      dst[(e_yy * SCOLS + 0) * PITCH + e_cin] = (_Float16)evA0;
      dst[(e_yy * SCOLS + 17) * PITCH + e_cin] = (_Float16)evA1;
    } else if (zA) {
      zero_slot(SLOT(ts0));
    }

    // ---- issue stage loads B (slice ts1) ----
    float svB[16], evB0 = 0.f, evB1 = 0.f;
    if (stB) {
      const float* sb = in + ((size_t)(b * CIN_) * T_ + ts1) * SP_;
#pragma unroll
      for (int kk = 0; kk < 16; ++kk) {
        int rj = kk * 16 + s_q;
        int cin = rj & 31;
        int yy = rj >> 5;
        int gy = y0 - 1 + yy;
        svB[kk] = 0.f;
        if ((unsigned)gy < (unsigned)H_)
          svB[kk] = sb[(size_t)cin * (T_ * SP_) + gy * W_ + x0 + s_xi];
      }
      if (e_ok) {
        const float* rb = sb + (size_t)e_cin * (T_ * SP_) + e_gy * W_;
        if (x0 > 0) evB0 = rb[x0 - 1];
        if (x0 + 16 < W_) evB1 = rb[x0 + 16];
      }
    }

    // ---- slices s=2,3: acc0 kd=2 (s==2); acc1 kd=1,2 ----
    // (t0==30 tail: s=3 reads stale slot, acc1 discarded — harmless)
#pragma unroll
    for (int s = 2; s < 4; ++s) {
      const _Float16* sb2 = in_s + SLOT(t0 - 1 + s) * SLICE_HF;
#pragma unroll
      for (int kw = 0; kw < 3; ++kw) {
        half8 brow[8];
#pragma unroll
        for (int rr = 0; rr < 8; ++rr)
          brow[rr] = *(const half8*)(sb2 + (rr * SCOLS + px + kw) * PITCH + kq * 8);
#pragma unroll
        for (int kh = 0; kh < 3; ++kh) {
          if (s == 2) {
            const int tap0 = 18 + kh * 3 + kw;
#pragma unroll
            for (int r = 0; r < 6; ++r)
              acc0[r] = __builtin_amdgcn_mfma_f32_16x16x32_f16(wreg[tap0], brow[r + kh], acc0[r], 0, 0, 0);
          }
          const int tap1 = (s - 1) * 9 + kh * 3 + kw;
#pragma unroll
          for (int r = 0; r < 6; ++r)
            acc1[r] = __builtin_amdgcn_mfma_f32_16x16x32_f16(wreg[tap1], brow[r + kh], acc1[r], 0, 0, 0);
        }
      }
    }

    // ---- write B (slot SLOT(t0+4) = SLOT(t0-2), outside read window) ----
    if (stB) {
      _Float16* dst = in_s + SLOT(ts1) * SLICE_HF;
#pragma unroll
      for (int kk = 0; kk < 16; ++kk) {
        int rj = kk * 16 + s_q;
        int cin = rj & 31;
        int yy = rj >> 5;
        dst[(yy * SCOLS + s_xi + 1) * PITCH + cin] = (_Float16)svB[kk];
      }
      dst[(e_yy * SCOLS + 0) * PITCH + e_cin] = (_Float16)evB0;
      dst[(e_yy * SCOLS + 17) * PITCH + e_cin] = (_Float16)evB1;
    } else if (zB) {
      zero_slot(SLOT(ts1));
    }

    // ---- activations + pack + store ----
    size_t ob0 = ((size_t)(b * HID_ + c0) * T_ + t0) * SP_ + y0 * W_ + x0 + px;
#pragma unroll
    for (int r = 0; r < 6; ++r) {
      float z0 = 1.f - 2.f / (1.f + __expf(2.f * acc0[r][0]));
      float f0 = 1.f / (1.f + __expf(-acc0[r][1]));
      gout[ob0 + r * W_] = packzf(z0, f0);
      float z1 = 1.f - 2.f / (1.f + __expf(2.f * acc0[r][2]));
      float f1 = 1.f / (1.f + __expf(-acc0[r][3]));
      gout[ob0 + (size_t)T_ * SP_ + r * W_] = packzf(z1, f1);
    }
    if (hasT1) {
      size_t ob1 = ob0 + SP_;
#pragma unroll
      for (int r = 0; r < 6; ++r) {
        float z0 = 1.f - 2.f / (1.f + __expf(2.f * acc1[r][0]));
        float f0 = 1.f / (1.f + __expf(-acc1[r][1]));
        gout[ob1 + r * W_] = packzf(z0, f0);
        float z1 = 1.f - 2.f / (1.f + __expf(2.f * acc1[r][2]));
        float f1 = 1.f / (1.f + __expf(-acc1[r][3]));
        gout[ob1 + (size_t)T_ * SP_ + r * W_] = packzf(z1, f1);
      }
    }
    __syncthreads();   // staged slices visible; ring safety for next pair
  }
}

// ---------------------------------------------------------------------------
// Kernel 2: fused time-recurrence scan + per-pixel channel attention,
// in-place on d_out (reads packed gates u32, writes final f32).
// Scan: thread (c,xi) walks t (coalesced 64B u32 runs), h in reg, writes
// qh/qt f16 to LDS. Then 32x32x16 MFMA attention as before.
// ---------------------------------------------------------------------------
#define APIT 40
#define PSTR 1288

__global__ __launch_bounds__(512) void attn_rec_mfma(
    unsigned int* __restrict__ g, const float* __restrict__ gamma) {
  __shared__ _Float16 qh_s[16 * PSTR];
  __shared__ _Float16 qt_s[16 * PSTR];
  __shared__ _Float16 at_s[8 * 32 * APIT];

  const int tid = threadIdx.x;
  const int x0 = blockIdx.x * 16;
  const int y = blockIdx.y;
  const int b = blockIdx.z;
  const int lane = tid & 63;
  const int wv = tid >> 6;
  const float gm = gamma[0];

  // ---- recurrence scan: thread = (c = tid>>4, xi = tid&15) ----
  {
    const int c = tid >> 4;
    const int xi = tid & 15;
    const unsigned int* gp =
        g + ((size_t)(b * HID_ + c) * T_) * SP_ + y * W_ + x0 + xi;
    float h = 0.f;
#pragma unroll
    for (int t = 0; t < T_; ++t) {
      unsigned int gw = gp[(size_t)t * SP_];
      float z = (float)__builtin_bit_cast(_Float16, (unsigned short)(gw & 0xffff));
      float f = (float)__builtin_bit_cast(_Float16, (unsigned short)(gw >> 16));
      h = f * (h - z) + z;               // f*h + (1-f)*z
      _Float16 hv = (_Float16)h;
      qh_s[xi * PSTR + c * APIT + t] = hv;
      qt_s[xi * PSTR + t * APIT + c] = hv;
    }
    qh_s[xi * PSTR + c * APIT + 31] = (_Float16)0.f;   // t-pad
  }
  __syncthreads();

  const int cd = lane & 31;
  const int hi = lane >> 5;

#pragma unroll
  for (int pp = 0; pp < 2; ++pp) {
    const int px = wv * 2 + pp;
    const _Float16* qs = qh_s + px * PSTR;
    const _Float16* qt = qt_s + px * PSTR;
    _Float16* as = at_s + wv * (32 * APIT);

    // QK^T: S[c][d] = sum_t qh[c][t] qh[d][t]
    half8 q0 = *(const half8*)(qs + cd * APIT + hi * 8);
    half8 q1 = *(const half8*)(qs + cd * APIT + hi * 8 + 16);
    f32x16 S = {};
    S = __builtin_amdgcn_mfma_f32_32x32x16_f16(q0, q0, S, 0, 0, 0);
    S = __builtin_amdgcn_mfma_f32_32x32x16_f16(q1, q1, S, 0, 0, 0);

    // softmax over c (rows in regs + lane^32), then * 1/sqrt(32)
    float mx = S[0];
#pragma unroll
    for (int r = 1; r < 16; ++r) mx = fmaxf(mx, S[r]);
    mx = fmaxf(mx, __shfl_xor(mx, 32));
    float sm = 0.f;
    float ev[16];
#pragma unroll
    for (int r = 0; r < 16; ++r) { ev[r] = __expf(S[r] - mx); sm += ev[r]; }
    sm += __shfl_xor(sm, 32);
    const float sc = 0.17677669529663688f / sm;

#pragma unroll
    for (int r = 0; r < 16; ++r) {
      int c = (r & 3) + 8 * (r >> 2) + 4 * hi;
      as[c * APIT + cd] = (_Float16)(ev[r] * sc);
    }

    // PV: P[c][t] = sum_d attn[c][d] qh[d][t]
    half8 a0 = *(const half8*)(as + cd * APIT + hi * 8);
    half8 a1 = *(const half8*)(as + cd * APIT + hi * 8 + 16);
    half8 b0 = *(const half8*)(qt + cd * APIT + hi * 8);
    half8 b1 = *(const half8*)(qt + cd * APIT + hi * 8 + 16);
    f32x16 P = {};
    P = __builtin_amdgcn_mfma_f32_32x32x16_f16(a0, b0, P, 0, 0, 0);
    P = __builtin_amdgcn_mfma_f32_32x32x16_f16(a1, b1, P, 0, 0, 0);

#pragma unroll
    for (int r = 0; r < 16; ++r) {
      int c = (r & 3) + 8 * (r >> 2) + 4 * hi;
      qt_s[px * PSTR + cd * APIT + c] = (_Float16)P[r];
    }
  }
  __syncthreads();

  // store: out = gamma * ah + h (float4 writes over the gates buffer)
  float* gf = (float*)g;
  for (int e = tid; e < 4 * 992; e += 512) {
    int xi4 = e & 3;
    int q = e >> 2;
    int t = q % 31;
    int c = q / 31;
    float4 rv;
#pragma unroll
    for (int j = 0; j < 4; ++j) {
      int xi = xi4 * 4 + j;
      float ah = (float)qt_s[xi * PSTR + t * APIT + c];
      float hv = (float)qh_s[xi * PSTR + c * APIT + t];
      (&rv.x)[j] = gm * ah + hv;
    }
    *(float4*)&gf[((size_t)(b * HID_ + c) * T_ + t) * SP_ + y * W_ + x0 +
                  xi4 * 4] = rv;
  }
}

// ---------------------------------------------------------------------------
extern "C" void kernel_launch(void* const* d_in, const int* in_sizes, int n_in,
                              void* d_out, int out_size, void* d_ws,
                              size_t ws_size, hipStream_t stream) {
  const float* in    = (const float*)d_in[0];  // [4,32,31,96,96]
  const float* w     = (const float*)d_in[1];  // [64,32,3,3,3]
  const float* bias  = (const float*)d_in[2];  // [64]
  const float* gamma = (const float*)d_in[3];  // [1]
  _Float16* wr = (_Float16*)d_ws;              // 110 KB fp16 fragments

  prep_w_kernel<<<216, 256, 0, stream>>>(w, wr);
  conv_gates_mfma<<<dim3(96, NCH_, 4), 256, 0, stream>>>(
      in, wr, bias, (unsigned int*)d_out);
  attn_rec_mfma<<<dim3(6, 96, 4), 512, 0, stream>>>(
      (unsigned int*)d_out, gamma);
}

// Round 10
// 282.794 us; speedup vs baseline: 1.7191x; 1.7191x over previous
//
#include <hip/hip_runtime.h>
#include <math.h>

#define B_ 4
#define CIN_ 32
#define HID_ 32
#define T_ 31
#define H_ 96
#define W_ 96
#define SP_ (H_*W_)

typedef _Float16 half8 __attribute__((ext_vector_type(8)));
typedef float f32x4 __attribute__((ext_vector_type(4)));
typedef float f32x16 __attribute__((ext_vector_type(16)));

static __device__ inline unsigned int packhh(float a, float b) {
  unsigned short ua = __builtin_bit_cast(unsigned short, (_Float16)a);
  unsigned short ub = __builtin_bit_cast(unsigned short, (_Float16)b);
  return (unsigned int)ua | ((unsigned int)ub << 16);
}

// ---------------------------------------------------------------------------
// Kernel 0: weights fp32 -> fp16 gate-interleaved MFMA A-fragments.
// wr[((ocg*27 + tap)*64 + lane)*8 + i]
//   m = lane&15: gate = m&1, ch = ocg*8 + (m>>1); oc = gate*32 + ch
//   cin = (lane>>4)*8 + i
// ---------------------------------------------------------------------------
__global__ __launch_bounds__(256) void prep_w_kernel(
    const float* __restrict__ w, _Float16* __restrict__ wr) {
  int idx = blockIdx.x * 256 + threadIdx.x;
  if (idx >= 55296) return;
  int i = idx & 7;
  int lane = (idx >> 3) & 63;
  int rest = idx >> 9;             // ocg*27 + tap
  int tap = rest % 27;
  int ocg = rest / 27;
  int m = lane & 15;
  int cin = (lane >> 4) * 8 + i;
  int oc = (m & 1) * 32 + ocg * 8 + (m >> 1);
  wr[idx] = (_Float16)(w[(oc * CIN_ + cin) * 27 + tap]);
}

// ---------------------------------------------------------------------------
// Kernel 1: fused Conv3d (fp16 MFMA) + gating + SERIAL time recurrence.
// == R6's proven 232us kernel ==, except h is stored packed fp16x2:
// lane owns channel pair (c0, c0+1); u32 = (f16(h0) | f16(h1)<<16) written to
// u32-plane b*32 + pr (pr = ocg*4+kq in 0..15) -> half the write traffic.
// Grid (96,4): tile 16x6. Block 256 thr = 4 waves (wave = ocg).
// Weights 27 half8 = 108 VGPR/wave. Ring: 4 slots x [8 rows x 18 cols]
// [pitch 40 f16] = 46 KB -> 2 blocks/CU.
// ---------------------------------------------------------------------------
#define PITCH 40
#define SROWS 8
#define SCOLS 18
#define SLICE_HF (SROWS * SCOLS * PITCH)   // 5760 f16 = 11520 B

__global__ __launch_bounds__(256, 2) void conv_rec_mfma(
    const float* __restrict__ in, const _Float16* __restrict__ wr,
    const float* __restrict__ bias, unsigned int* __restrict__ gout) {
  __shared__ _Float16 in_s[4 * SLICE_HF];   // 46080 B

  const int tid = threadIdx.x;
  const int tile = blockIdx.x;   // 0..95
  const int b = blockIdx.y;      // 0..3
  const int x0 = (tile % 6) * 16;
  const int y0 = (tile / 6) * 6;
  const int lane = tid & 63;
  const int ocg = tid >> 6;      // 0..3
  const int px = lane & 15;
  const int kq = lane >> 4;      // 0..3

  // per-wave weights: 27 taps, gate-interleaved 16-slot frags (108 VGPR)
  half8 wreg[27];
  {
    const _Float16* wp = wr + (size_t)ocg * 27 * 512 + lane * 8;
#pragma unroll
    for (int tap = 0; tap < 27; ++tap)
      wreg[tap] = *(const half8*)(wp + tap * 512);
  }

  const int c0 = ocg * 8 + 2 * kq;
  f32x4 bias4;
  bias4[0] = bias[c0];
  bias4[1] = bias[32 + c0];
  bias4[2] = bias[c0 + 1];
  bias4[3] = bias[32 + c0 + 1];

  // staging roles: interior 16 jobs x 16 px (256 rowjobs = 8 rows x 32 cin)
  const int s_xi = tid & 15;
  const int s_q  = tid >> 4;
  const int e_cin = tid & 31;
  const int e_yy  = tid >> 5;       // 0..7
  const int e_gy  = y0 - 1 + e_yy;
  const bool e_ok = ((unsigned)e_gy < (unsigned)H_);

  auto stage_full = [&](int ts) {
    _Float16* dst = in_s + (ts & 3) * SLICE_HF;
    const float* sb = in + ((size_t)(b * CIN_) * T_ + ts) * SP_;
#pragma unroll
    for (int k = 0; k < 16; ++k) {
      int rj = k * 16 + s_q;          // yy*32 + cin
      int cin = rj & 31;
      int yy = rj >> 5;
      int gy = y0 - 1 + yy;
      float v = 0.f;
      if ((unsigned)gy < (unsigned)H_)
        v = sb[(size_t)cin * (T_ * SP_) + gy * W_ + x0 + s_xi];
      dst[(yy * SCOLS + s_xi + 1) * PITCH + cin] = (_Float16)v;
    }
    float v0 = 0.f, v1 = 0.f;
    if (e_ok) {
      const float* rb = sb + (size_t)e_cin * (T_ * SP_) + e_gy * W_;
      if (x0 > 0) v0 = rb[x0 - 1];
      if (x0 + 16 < W_) v1 = rb[x0 + 16];
    }
    dst[(e_yy * SCOLS + 0) * PITCH + e_cin] = (_Float16)v0;
    dst[(e_yy * SCOLS + 17) * PITCH + e_cin] = (_Float16)v1;
  };

  // prologue: slot 3 = slice -1 = zeros (single pass, no race); 0,1 staged
  {
    uint32_t* dz = (uint32_t*)(in_s + 3 * SLICE_HF);
    for (int e = tid; e < SLICE_HF / 2; e += 256) dz[e] = 0u;
  }
  stage_full(0);
  stage_full(1);
  __syncthreads();

  float h[6][2];
#pragma unroll
  for (int r = 0; r < 6; ++r) { h[r][0] = 0.f; h[r][1] = 0.f; }

  const int pr = ocg * 4 + kq;   // packed pair plane 0..15
  size_t obase = ((size_t)(b * 32 + pr) * T_) * SP_ + y0 * W_ + x0 + px;

  for (int t = 0; t < T_; ++t) {
    const int ts = t + 2;

    // ---- phase A: issue stage loads for slice ts (held in regs) ----
    float sv[16], ev0 = 0.f, ev1 = 0.f;
    if (ts < T_) {
      const float* sb = in + ((size_t)(b * CIN_) * T_ + ts) * SP_;
#pragma unroll
      for (int k = 0; k < 16; ++k) {
        int rj = k * 16 + s_q;
        int cin = rj & 31;
        int yy = rj >> 5;
        int gy = y0 - 1 + yy;
        sv[k] = 0.f;
        if ((unsigned)gy < (unsigned)H_)
          sv[k] = sb[(size_t)cin * (T_ * SP_) + gy * W_ + x0 + s_xi];
      }
      if (e_ok) {
        const float* rb = sb + (size_t)e_cin * (T_ * SP_) + e_gy * W_;
        if (x0 > 0) ev0 = rb[x0 - 1];
        if (x0 + 16 < W_) ev1 = rb[x0 + 16];
      }
    }

    // ---- compute: 27 taps x 6 rows ----
    f32x4 acc[6];
#pragma unroll
    for (int r = 0; r < 6; ++r) acc[r] = bias4;

#pragma unroll
    for (int kd = 0; kd < 3; ++kd) {
      const _Float16* sb2 = in_s + ((t + 3 + kd) & 3) * SLICE_HF;  // slice t-1+kd
#pragma unroll
      for (int kw = 0; kw < 3; ++kw) {
        half8 brow[8];
#pragma unroll
        for (int rr = 0; rr < 8; ++rr)
          brow[rr] = *(const half8*)(sb2 + (rr * SCOLS + px + kw) * PITCH + kq * 8);
#pragma unroll
        for (int kh = 0; kh < 3; ++kh) {
          const int tap = kd * 9 + kh * 3 + kw;
#pragma unroll
          for (int r = 0; r < 6; ++r)
            acc[r] = __builtin_amdgcn_mfma_f32_16x16x32_f16(wreg[tap], brow[r + kh], acc[r], 0, 0, 0);
        }
      }
    }

    // ---- phase B: write staged slice to ring slot (t+2)&3 ----
    if (ts < T_) {
      _Float16* dst = in_s + (ts & 3) * SLICE_HF;
#pragma unroll
      for (int k = 0; k < 16; ++k) {
        int rj = k * 16 + s_q;
        int cin = rj & 31;
        int yy = rj >> 5;
        dst[(yy * SCOLS + s_xi + 1) * PITCH + cin] = (_Float16)sv[k];
      }
      dst[(e_yy * SCOLS + 0) * PITCH + e_cin] = (_Float16)ev0;
      dst[(e_yy * SCOLS + 17) * PITCH + e_cin] = (_Float16)ev1;
    } else if (ts == T_) {
      uint32_t* dz = (uint32_t*)(in_s + (ts & 3) * SLICE_HF);
      for (int e = tid; e < SLICE_HF / 2; e += 256) dz[e] = 0u;
    }

    // ---- gating + recurrence + packed store (channel pair in-lane) ----
#pragma unroll
    for (int r = 0; r < 6; ++r) {
      float z0 = 1.f - 2.f / (1.f + __expf(2.f * acc[r][0]));
      float f0 = 1.f / (1.f + __expf(-acc[r][1]));
      h[r][0] = f0 * h[r][0] + (1.f - f0) * z0;
      float z1 = 1.f - 2.f / (1.f + __expf(2.f * acc[r][2]));
      float f1 = 1.f / (1.f + __expf(-acc[r][3]));
      h[r][1] = f1 * h[r][1] + (1.f - f1) * z1;
      gout[obase + r * W_] = packhh(h[r][0], h[r][1]);
    }
    obase += SP_;
    __syncthreads();   // stage writes visible; ring slot safety
  }
}

// ---------------------------------------------------------------------------
// Kernel 2: per-pixel channel attention via 32x32x16 MFMA.
// Reads packed f16x2 h from u32-planes b*32+pr (pr<16) at own (y,x) tile;
// writes final f32 to planes b*32+c at the SAME (y,x) tile -> no cross-block
// aliasing (each block owns its spatial positions; batch planes disjoint).
// PX=16/block, 512 thr; plane stride 1288 halfs (2-way bank = free).
// ---------------------------------------------------------------------------
#define APIT 40
#define PSTR 1288

__global__ __launch_bounds__(512) void attn_mfma(
    unsigned int* __restrict__ g, const float* __restrict__ gamma) {
  __shared__ _Float16 qh_s[16 * PSTR];      // 41216 B
  __shared__ _Float16 qt_s[16 * PSTR];      // 41216 B
  __shared__ _Float16 at_s[8 * 32 * APIT];  // 20480 B

  const int tid = threadIdx.x;
  const int x0 = blockIdx.x * 16;
  const int y = blockIdx.y;
  const int b = blockIdx.z;
  const int lane = tid & 63;
  const int wv = tid >> 6;       // 0..7
  const float gm = gamma[0];

  // stage packed h: 16 px x 16 pairs x 31 t u32 reads (64B runs), unpack
  for (int e = tid; e < 16 * 16 * 31; e += 512) {
    int xi = e & 15;
    int q = e >> 4;
    int t = q % 31;
    int pr = q / 31;
    unsigned int gw = g[((size_t)(b * 32 + pr) * T_ + t) * SP_ + y * W_ + x0 + xi];
    _Float16 h0 = __builtin_bit_cast(_Float16, (unsigned short)(gw & 0xffff));
    _Float16 h1 = __builtin_bit_cast(_Float16, (unsigned short)(gw >> 16));
    int c0 = 2 * pr;
    qh_s[xi * PSTR + c0 * APIT + t] = h0;
    qh_s[xi * PSTR + (c0 + 1) * APIT + t] = h1;
    qt_s[xi * PSTR + t * APIT + c0] = h0;
    qt_s[xi * PSTR + t * APIT + c0 + 1] = h1;
  }
  // zero-pad t=31 of qh (16 px x 32 c = 512 elems)
  qh_s[(tid & 15) * PSTR + (tid >> 4) * APIT + 31] = (_Float16)0.f;
  __syncthreads();

  const int cd = lane & 31;
  const int hi = lane >> 5;

#pragma unroll
  for (int pp = 0; pp < 2; ++pp) {
    const int px = wv * 2 + pp;
    const _Float16* qs = qh_s + px * PSTR;
    const _Float16* qt = qt_s + px * PSTR;
    _Float16* as = at_s + wv * (32 * APIT);

    // QK^T: S[c][d] = sum_t qh[c][t] qh[d][t]
    half8 q0 = *(const half8*)(qs + cd * APIT + hi * 8);
    half8 q1 = *(const half8*)(qs + cd * APIT + hi * 8 + 16);
    f32x16 S = {};
    S = __builtin_amdgcn_mfma_f32_32x32x16_f16(q0, q0, S, 0, 0, 0);
    S = __builtin_amdgcn_mfma_f32_32x32x16_f16(q1, q1, S, 0, 0, 0);

    // softmax over c (rows in regs + lane^32), then * 1/sqrt(32)
    float mx = S[0];
#pragma unroll
    for (int r = 1; r < 16; ++r) mx = fmaxf(mx, S[r]);
    mx = fmaxf(mx, __shfl_xor(mx, 32));
    float sm = 0.f;
    float ev[16];
#pragma unroll
    for (int r = 0; r < 16; ++r) { ev[r] = __expf(S[r] - mx); sm += ev[r]; }
    sm += __shfl_xor(sm, 32);
    const float sc = 0.17677669529663688f / sm;

#pragma unroll
    for (int r = 0; r < 16; ++r) {
      int c = (r & 3) + 8 * (r >> 2) + 4 * hi;
      as[c * APIT + cd] = (_Float16)(ev[r] * sc);
    }

    // PV: P[c][t] = sum_d attn[c][d] qh[d][t]
    half8 a0 = *(const half8*)(as + cd * APIT + hi * 8);
    half8 a1 = *(const half8*)(as + cd * APIT + hi * 8 + 16);
    half8 b0 = *(const half8*)(qt + cd * APIT + hi * 8);
    half8 b1 = *(const half8*)(qt + cd * APIT + hi * 8 + 16);
    f32x16 P = {};
    P = __builtin_amdgcn_mfma_f32_32x32x16_f16(a0, b0, P, 0, 0, 0);
    P = __builtin_amdgcn_mfma_f32_32x32x16_f16(a1, b1, P, 0, 0, 0);

    // result (lane holds t = cd, c in regs) -> qt[t*APIT + c]
#pragma unroll
    for (int r = 0; r < 16; ++r) {
      int c = (r & 3) + 8 * (r >> 2) + 4 * hi;
      qt_s[px * PSTR + cd * APIT + c] = (_Float16)P[r];
    }
  }
  __syncthreads();

  // store: out = gamma * ah + h (float4 writes over full f32 planes)
  float* gf = (float*)g;
  for (int e = tid; e < 4 * 992; e += 512) {
    int xi4 = e & 3;
    int q = e >> 2;
    int t = q % 31;
    int c = q / 31;
    float4 rv;
#pragma unroll
    for (int j = 0; j < 4; ++j) {
      int xi = xi4 * 4 + j;
      float ah = (float)qt_s[xi * PSTR + t * APIT + c];
      float hv = (float)qh_s[xi * PSTR + c * APIT + t];
      (&rv.x)[j] = gm * ah + hv;
    }
    *(float4*)&gf[((size_t)(b * HID_ + c) * T_ + t) * SP_ + y * W_ + x0 +
                  xi4 * 4] = rv;
  }
}

// ---------------------------------------------------------------------------
extern "C" void kernel_launch(void* const* d_in, const int* in_sizes, int n_in,
                              void* d_out, int out_size, void* d_ws,
                              size_t ws_size, hipStream_t stream) {
  const float* in    = (const float*)d_in[0];  // [4,32,31,96,96]
  const float* w     = (const float*)d_in[1];  // [64,32,3,3,3]
  const float* bias  = (const float*)d_in[2];  // [64]
  const float* gamma = (const float*)d_in[3];  // [1]
  _Float16* wr = (_Float16*)d_ws;              // 110 KB fp16 fragments

  prep_w_kernel<<<216, 256, 0, stream>>>(w, wr);
  conv_rec_mfma<<<dim3(96, 4), 256, 0, stream>>>(
      in, wr, bias, (unsigned int*)d_out);
  attn_mfma<<<dim3(6, 96, 4), 512, 0, stream>>>(
      (unsigned int*)d_out, gamma);
}

// Round 11
// 277.778 us; speedup vs baseline: 1.7501x; 1.0181x over previous
//
#include <hip/hip_runtime.h>
#include <math.h>

#define B_ 4
#define CIN_ 32
#define HID_ 32
#define T_ 31
#define H_ 96
#define W_ 96
#define SP_ (H_*W_)
#define TSP (T_ * SP_)

typedef _Float16 half8 __attribute__((ext_vector_type(8)));
typedef float f32x4 __attribute__((ext_vector_type(4)));
typedef float f32x16 __attribute__((ext_vector_type(16)));

static __device__ inline unsigned int packhh(float a, float b) {
  unsigned short ua = __builtin_bit_cast(unsigned short, (_Float16)a);
  unsigned short ub = __builtin_bit_cast(unsigned short, (_Float16)b);
  return (unsigned int)ua | ((unsigned int)ub << 16);
}

// ---------------------------------------------------------------------------
// Kernel 0: weights fp32 -> fp16 gate-interleaved MFMA A-fragments.
// wr[((ocg*27 + tap)*64 + lane)*8 + i]
//   m = lane&15: gate = m&1, ch = ocg*8 + (m>>1); oc = gate*32 + ch
//   cin = (lane>>4)*8 + i
// ---------------------------------------------------------------------------
__global__ __launch_bounds__(256) void prep_w_kernel(
    const float* __restrict__ w, _Float16* __restrict__ wr) {
  int idx = blockIdx.x * 256 + threadIdx.x;
  if (idx >= 55296) return;
  int i = idx & 7;
  int lane = (idx >> 3) & 63;
  int rest = idx >> 9;             // ocg*27 + tap
  int tap = rest % 27;
  int ocg = rest / 27;
  int m = lane & 15;
  int cin = (lane >> 4) * 8 + i;
  int oc = (m & 1) * 32 + ocg * 8 + (m >> 1);
  wr[idx] = (_Float16)(w[(oc * CIN_ + cin) * 27 + tap]);
}

// ---------------------------------------------------------------------------
// Kernel 1: fused Conv3d (fp16 MFMA) + gating + SERIAL time recurrence.
// R10 structure (proven 215us) + three micro-opts:
//  (a) h-stores AFTER the barrier (pre-barrier vmcnt(0) no longer waits
//      global store retirement every t),
//  (b) cin XOR-swizzle: element (c,cin) stored at cin^((c&8)?16:0) — breaks
//      the (px,px+8) same-bank alias on brow ds_read_b128 (bijective, block
//      contiguity preserved; reads use kq*8 ^ same mask),
//  (c) staging addresses hoisted to thread-const bases + k-constants
//      (yy = k>>1, cin = (k&1)*16+s_q); row validity is wave-uniform.
// Grid (96,4): tile 16x6. Block 256 thr = 4 waves (wave = ocg).
// Ring: 4 slots x [8 rows x 18 cols][pitch 40 f16] = 46 KB -> 2 blocks/CU.
// ---------------------------------------------------------------------------
#define PITCH 40
#define SROWS 8
#define SCOLS 18
#define RST (SCOLS * PITCH)                // 720 halfs per LDS row
#define SLICE_HF (SROWS * RST)             // 5760 f16 = 11520 B

__global__ __launch_bounds__(256, 2) void conv_rec_mfma(
    const float* __restrict__ in, const _Float16* __restrict__ wr,
    const float* __restrict__ bias, unsigned int* __restrict__ gout) {
  __shared__ _Float16 in_s[4 * SLICE_HF];   // 46080 B

  const int tid = threadIdx.x;
  const int tile = blockIdx.x;   // 0..95
  const int b = blockIdx.y;      // 0..3
  const int x0 = (tile % 6) * 16;
  const int y0 = (tile / 6) * 6;
  const int lane = tid & 63;
  const int ocg = tid >> 6;      // 0..3
  const int px = lane & 15;
  const int kq = lane >> 4;      // 0..3

  // per-wave weights: 27 taps, gate-interleaved 16-slot frags (108 VGPR)
  half8 wreg[27];
  {
    const _Float16* wp = wr + (size_t)ocg * 27 * 512 + lane * 8;
#pragma unroll
    for (int tap = 0; tap < 27; ++tap)
      wreg[tap] = *(const half8*)(wp + tap * 512);
  }

  const int c0 = ocg * 8 + 2 * kq;
  f32x4 bias4;
  bias4[0] = bias[c0];
  bias4[1] = bias[32 + c0];
  bias4[2] = bias[c0 + 1];
  bias4[3] = bias[32 + c0 + 1];

  // ---- staging thread-const bases (opt c) ----
  const int s_xi = tid & 15;
  const int s_q  = tid >> 4;       // 0..15
  // interior: job k -> yy = k>>1, cin = (k&1)*16 + s_q, col = s_xi+1
  const int ibase = s_q * TSP + (y0 - 1) * W_ + x0 + s_xi;
  const int wxm   = ((s_xi + 1) & 8) ? 1 : 0;          // swizzle bit for col
  const int wbase = (s_xi + 1) * PITCH + s_q;
  // edges: lane -> (e_yy = tid>>5, e_cin = tid&31), cols 0 and 17 (no swz)
  const int e_cin = tid & 31;
  const int e_yy  = tid >> 5;
  const int e_gy  = y0 - 1 + e_yy;
  const bool e_ok = ((unsigned)e_gy < (unsigned)H_);
  const int eoff  = e_cin * TSP + e_gy * W_;
  const int ew0   = e_yy * RST + 0 * PITCH + e_cin;
  const int ew1   = e_yy * RST + 17 * PITCH + e_cin;
  const bool has_l = (x0 > 0), has_r = (x0 + 16 < W_);

  // brow column offsets (opt b): col c = px+kw, swz = (c&8)?16:0 applied to kq*8
  int cs[3];
#pragma unroll
  for (int kw = 0; kw < 3; ++kw) {
    int c = px + kw;
    cs[kw] = c * PITCH + ((kq * 8) ^ ((c & 8) ? 16 : 0));
  }

  const float* inb = in + (size_t)(b * CIN_) * TSP;

  auto stage_full = [&](int ts) {   // prologue only
    _Float16* dst = in_s + (ts & 3) * SLICE_HF;
    const int tso = ts * SP_;
#pragma unroll
    for (int k = 0; k < 16; ++k) {
      const int gy = y0 - 1 + (k >> 1);       // wave-uniform validity
      float v = 0.f;
      if ((unsigned)gy < (unsigned)H_)
        v = inb[ibase + (k & 1) * 16 * TSP + (k >> 1) * W_ + tso];
      dst[wbase + (k >> 1) * RST + (((k & 1) ^ wxm) * 16)] = (_Float16)v;
    }
    float v0 = 0.f, v1 = 0.f;
    if (e_ok) {
      if (has_l) v0 = inb[eoff + tso + x0 - 1];
      if (has_r) v1 = inb[eoff + tso + x0 + 16];
    }
    dst[ew0] = (_Float16)v0;
    dst[ew1] = (_Float16)v1;
  };

  // prologue: slot 3 = slice -1 = zeros (single pass); slices 0,1 staged
  {
    uint32_t* dz = (uint32_t*)(in_s + 3 * SLICE_HF);
    for (int e = tid; e < SLICE_HF / 2; e += 256) dz[e] = 0u;
  }
  stage_full(0);
  stage_full(1);
  __syncthreads();

  float h[6][2];
#pragma unroll
  for (int r = 0; r < 6; ++r) { h[r][0] = 0.f; h[r][1] = 0.f; }

  const int pr = ocg * 4 + kq;   // packed pair plane 0..15
  size_t obase = ((size_t)(b * 32 + pr) * T_) * SP_ + y0 * W_ + x0 + px;

  for (int t = 0; t < T_; ++t) {
    const int ts = t + 2;

    // ---- phase A: issue stage loads for slice ts (held in regs) ----
    float sv[16], ev0 = 0.f, ev1 = 0.f;
    if (ts < T_) {
      const int tso = ts * SP_;
#pragma unroll
      for (int k = 0; k < 16; ++k) {
        const int gy = y0 - 1 + (k >> 1);
        sv[k] = 0.f;
        if ((unsigned)gy < (unsigned)H_)
          sv[k] = inb[ibase + (k & 1) * 16 * TSP + (k >> 1) * W_ + tso];
      }
      if (e_ok) {
        if (has_l) ev0 = inb[eoff + tso + x0 - 1];
        if (has_r) ev1 = inb[eoff + tso + x0 + 16];
      }
    }

    // ---- compute: 27 taps x 6 rows ----
    f32x4 acc[6];
#pragma unroll
    for (int r = 0; r < 6; ++r) acc[r] = bias4;

#pragma unroll
    for (int kd = 0; kd < 3; ++kd) {
      const _Float16* sb2 = in_s + ((t + 3 + kd) & 3) * SLICE_HF;  // slice t-1+kd
#pragma unroll
      for (int kw = 0; kw < 3; ++kw) {
        half8 brow[8];
#pragma unroll
        for (int rr = 0; rr < 8; ++rr)
          brow[rr] = *(const half8*)(sb2 + rr * RST + cs[kw]);
#pragma unroll
        for (int kh = 0; kh < 3; ++kh) {
          const int tap = kd * 9 + kh * 3 + kw;
#pragma unroll
          for (int r = 0; r < 6; ++r)
            acc[r] = __builtin_amdgcn_mfma_f32_16x16x32_f16(wreg[tap], brow[r + kh], acc[r], 0, 0, 0);
        }
      }
    }

    // ---- phase B: write staged slice to ring slot (t+2)&3 ----
    if (ts < T_) {
      _Float16* dst = in_s + (ts & 3) * SLICE_HF;
#pragma unroll
      for (int k = 0; k < 16; ++k)
        dst[wbase + (k >> 1) * RST + (((k & 1) ^ wxm) * 16)] = (_Float16)sv[k];
      dst[ew0] = (_Float16)ev0;
      dst[ew1] = (_Float16)ev1;
    } else if (ts == T_) {
      uint32_t* dz = (uint32_t*)(in_s + (ts & 3) * SLICE_HF);
      for (int e = tid; e < SLICE_HF / 2; e += 256) dz[e] = 0u;
    }

    // ---- gating + recurrence (packed into regs) ----
    unsigned int pk[6];
#pragma unroll
    for (int r = 0; r < 6; ++r) {
      float z0 = 1.f - 2.f / (1.f + __expf(2.f * acc[r][0]));
      float f0 = 1.f / (1.f + __expf(-acc[r][1]));
      h[r][0] = f0 * h[r][0] + (1.f - f0) * z0;
      float z1 = 1.f - 2.f / (1.f + __expf(2.f * acc[r][2]));
      float f1 = 1.f / (1.f + __expf(-acc[r][3]));
      h[r][1] = f1 * h[r][1] + (1.f - f1) * z1;
      pk[r] = packhh(h[r][0], h[r][1]);
    }
    __syncthreads();   // stage writes visible; ring slot safety

    // ---- h-stores AFTER the barrier (opt a): drain covered by next barrier
#pragma unroll
    for (int r = 0; r < 6; ++r)
      gout[obase + r * W_] = pk[r];
    obase += SP_;
  }
}

// ---------------------------------------------------------------------------
// Kernel 2: per-pixel channel attention via 32x32x16 MFMA. (R10, unchanged)
// Reads packed f16x2 h from u32-planes b*32+pr at own (y,x) tile; writes
// final f32 to planes b*32+c at the same tile -> no cross-block aliasing.
// ---------------------------------------------------------------------------
#define APIT 40
#define PSTR 1288

__global__ __launch_bounds__(512) void attn_mfma(
    unsigned int* __restrict__ g, const float* __restrict__ gamma) {
  __shared__ _Float16 qh_s[16 * PSTR];      // 41216 B
  __shared__ _Float16 qt_s[16 * PSTR];      // 41216 B
  __shared__ _Float16 at_s[8 * 32 * APIT];  // 20480 B

  const int tid = threadIdx.x;
  const int x0 = blockIdx.x * 16;
  const int y = blockIdx.y;
  const int b = blockIdx.z;
  const int lane = tid & 63;
  const int wv = tid >> 6;       // 0..7
  const float gm = gamma[0];

  for (int e = tid; e < 16 * 16 * 31; e += 512) {
    int xi = e & 15;
    int q = e >> 4;
    int t = q % 31;
    int pr = q / 31;
    unsigned int gw = g[((size_t)(b * 32 + pr) * T_ + t) * SP_ + y * W_ + x0 + xi];
    _Float16 h0 = __builtin_bit_cast(_Float16, (unsigned short)(gw & 0xffff));
    _Float16 h1 = __builtin_bit_cast(_Float16, (unsigned short)(gw >> 16));
    int c0 = 2 * pr;
    qh_s[xi * PSTR + c0 * APIT + t] = h0;
    qh_s[xi * PSTR + (c0 + 1) * APIT + t] = h1;
    qt_s[xi * PSTR + t * APIT + c0] = h0;
    qt_s[xi * PSTR + t * APIT + c0 + 1] = h1;
  }
  qh_s[(tid & 15) * PSTR + (tid >> 4) * APIT + 31] = (_Float16)0.f;
  __syncthreads();

  const int cd = lane & 31;
  const int hi = lane >> 5;

#pragma unroll
  for (int pp = 0; pp < 2; ++pp) {
    const int px = wv * 2 + pp;
    const _Float16* qs = qh_s + px * PSTR;
    const _Float16* qt = qt_s + px * PSTR;
    _Float16* as = at_s + wv * (32 * APIT);

    half8 q0 = *(const half8*)(qs + cd * APIT + hi * 8);
    half8 q1 = *(const half8*)(qs + cd * APIT + hi * 8 + 16);
    f32x16 S = {};
    S = __builtin_amdgcn_mfma_f32_32x32x16_f16(q0, q0, S, 0, 0, 0);
    S = __builtin_amdgcn_mfma_f32_32x32x16_f16(q1, q1, S, 0, 0, 0);

    float mx = S[0];
#pragma unroll
    for (int r = 1; r < 16; ++r) mx = fmaxf(mx, S[r]);
    mx = fmaxf(mx, __shfl_xor(mx, 32));
    float sm = 0.f;
    float ev[16];
#pragma unroll
    for (int r = 0; r < 16; ++r) { ev[r] = __expf(S[r] - mx); sm += ev[r]; }
    sm += __shfl_xor(sm, 32);
    const float sc = 0.17677669529663688f / sm;

#pragma unroll
    for (int r = 0; r < 16; ++r) {
      int c = (r & 3) + 8 * (r >> 2) + 4 * hi;
      as[c * APIT + cd] = (_Float16)(ev[r] * sc);
    }

    half8 a0 = *(const half8*)(as + cd * APIT + hi * 8);
    half8 a1 = *(const half8*)(as + cd * APIT + hi * 8 + 16);
    half8 b0 = *(const half8*)(qt + cd * APIT + hi * 8);
    half8 b1 = *(const half8*)(qt + cd * APIT + hi * 8 + 16);
    f32x16 P = {};
    P = __builtin_amdgcn_mfma_f32_32x32x16_f16(a0, b0, P, 0, 0, 0);
    P = __builtin_amdgcn_mfma_f32_32x32x16_f16(a1, b1, P, 0, 0, 0);

#pragma unroll
    for (int r = 0; r < 16; ++r) {
      int c = (r & 3) + 8 * (r >> 2) + 4 * hi;
      qt_s[px * PSTR + cd * APIT + c] = (_Float16)P[r];
    }
  }
  __syncthreads();

  float* gf = (float*)g;
  for (int e = tid; e < 4 * 992; e += 512) {
    int xi4 = e & 3;
    int q = e >> 2;
    int t = q % 31;
    int c = q / 31;
    float4 rv;
#pragma unroll
    for (int j = 0; j < 4; ++j) {
      int xi = xi4 * 4 + j;
      float ah = (float)qt_s[xi * PSTR + t * APIT + c];
      float hv = (float)qh_s[xi * PSTR + c * APIT + t];
      (&rv.x)[j] = gm * ah + hv;
    }
    *(float4*)&gf[((size_t)(b * HID_ + c) * T_ + t) * SP_ + y * W_ + x0 +
                  xi4 * 4] = rv;
  }
}

// ---------------------------------------------------------------------------
extern "C" void kernel_launch(void* const* d_in, const int* in_sizes, int n_in,
                              void* d_out, int out_size, void* d_ws,
                              size_t ws_size, hipStream_t stream) {
  const float* in    = (const float*)d_in[0];  // [4,32,31,96,96]
  const float* w     = (const float*)d_in[1];  // [64,32,3,3,3]
  const float* bias  = (const float*)d_in[2];  // [64]
  const float* gamma = (const float*)d_in[3];  // [1]
  _Float16* wr = (_Float16*)d_ws;              // 110 KB fp16 fragments

  prep_w_kernel<<<216, 256, 0, stream>>>(w, wr);
  conv_rec_mfma<<<dim3(96, 4), 256, 0, stream>>>(
      in, wr, bias, (unsigned int*)d_out);
  attn_mfma<<<dim3(6, 96, 4), 512, 0, stream>>>(
      (unsigned int*)d_out, gamma);
}